// Round 1
// baseline (744.764 us; speedup 1.0000x reference)
//
#include <hip/hip_runtime.h>

#define CS 128   // chunk size
#define DH 64    // head dim
#define DS 128   // state dim
#define NC 32    // num chunks
#define NBH 64   // B*H
#define SEQ 4096

// ---------------- Phase 1: per-chunk h_contrib = B^T diag(decay_to_end) X ----------------
__global__ __launch_bounds__(256) void p1_hcontrib(
    const float* __restrict__ A, const float* __restrict__ X,
    const float* __restrict__ B, float* __restrict__ hbuf,
    float* __restrict__ dtot)
{
  __shared__ float csum[CS];
  __shared__ float Bs[32][DS + 4];
  __shared__ float Xs[32][DH + 4];

  const int blk = blockIdx.x;
  const int bh  = blk >> 5;
  const int c   = blk & 31;
  const int tid = threadIdx.x;

  const float* Ac = A + bh * SEQ + c * CS;
  const float* Xc = X + (size_t)(bh * SEQ + c * CS) * DH;
  const float* Bc = B + (size_t)(bh * SEQ + c * CS) * DS;
  float* hout = hbuf + (size_t)blk * DS * DH;

  // inclusive cumsum of Ac (Hillis-Steele, 128 lanes)
  if (tid < CS) csum[tid] = Ac[tid];
  __syncthreads();
  for (int off = 1; off < CS; off <<= 1) {
    float v = 0.f;
    if (tid < CS) { v = csum[tid]; if (tid >= off) v += csum[tid - off]; }
    __syncthreads();
    if (tid < CS) csum[tid] = v;
    __syncthreads();
  }
  const float cl = csum[CS - 1];
  if (tid == 0) dtot[blk] = __expf(cl);

  const int ty = tid >> 4, tx = tid & 15;
  float acc[8][4];
#pragma unroll
  for (int i = 0; i < 8; i++)
#pragma unroll
    for (int j = 0; j < 4; j++) acc[i][j] = 0.f;

  for (int kt = 0; kt < 4; ++kt) {
    const int t0 = kt * 32;
    // stage B tile [t][s]: 1024 float4, 4/thread
#pragma unroll
    for (int m = 0; m < 4; m++) {
      int q = m * 256 + tid;
      int r = q >> 5, c4 = q & 31;
      float4 v = *(const float4*)(Bc + (size_t)(t0 + r) * DS + c4 * 4);
      *(float4*)(&Bs[r][c4 * 4]) = v;
    }
    // stage X tile scaled by decay_to_end: 512 float4, 2/thread
#pragma unroll
    for (int m = 0; m < 2; m++) {
      int q = m * 256 + tid;
      int r = q >> 4, c4 = q & 15;
      float e = __expf(cl - csum[t0 + r]);
      float4 v = *(const float4*)(Xc + (size_t)(t0 + r) * DH + c4 * 4);
      v.x *= e; v.y *= e; v.z *= e; v.w *= e;
      *(float4*)(&Xs[r][c4 * 4]) = v;
    }
    __syncthreads();
#pragma unroll
    for (int k = 0; k < 32; k++) {
      float4 b0 = *(const float4*)(&Bs[k][ty * 8]);
      float4 b1 = *(const float4*)(&Bs[k][ty * 8 + 4]);
      float4 xv = *(const float4*)(&Xs[k][tx * 4]);
      float bb[8] = {b0.x, b0.y, b0.z, b0.w, b1.x, b1.y, b1.z, b1.w};
      float xx[4] = {xv.x, xv.y, xv.z, xv.w};
#pragma unroll
      for (int i = 0; i < 8; i++)
#pragma unroll
        for (int j = 0; j < 4; j++)
          acc[i][j] = fmaf(bb[i], xx[j], acc[i][j]);
    }
    __syncthreads();
  }
#pragma unroll
  for (int i = 0; i < 8; i++) {
    float4 v = {acc[i][0], acc[i][1], acc[i][2], acc[i][3]};
    *(float4*)(hout + (size_t)(ty * 8 + i) * DH + tx * 4) = v;
  }
}

// ---------------- Phase 2: in-place scan h_contrib[c] -> h_state[c], emit h_final ----------------
__global__ __launch_bounds__(256) void p2_scan(
    const float* __restrict__ h0, const float* __restrict__ dtot,
    float* __restrict__ hbuf, float* __restrict__ hfinal)
{
  int g = blockIdx.x * 256 + threadIdx.x;   // 0 .. 524287
  int bh = g >> 13;                         // / 8192
  int e  = g & 8191;
  float s = h0[g];
  const float* dt = dtot + bh * NC;
  float* p = hbuf + (size_t)bh * NC * 8192 + e;
#pragma unroll 1
  for (int cc = 0; cc < NC; ++cc) {
    float hc = p[(size_t)cc * 8192];
    p[(size_t)cc * 8192] = s;               // state at START of chunk cc
    s = fmaf(dt[cc], s, hc);
  }
  hfinal[g] = s;
}

// ---------------- Phase 3: Y = (L .* C B^T) X + diag(exp(csum)) C h_state ----------------
__global__ __launch_bounds__(256, 3) void p3_y(
    const float* __restrict__ A, const float* __restrict__ X,
    const float* __restrict__ B, const float* __restrict__ C,
    const float* __restrict__ hbuf, float* __restrict__ Y)
{
  __shared__ float csum[CS];
  __shared__ float SA[32][CS + 4];  // C (transposed) in stage A, then T (masked CB) per j-tile
  __shared__ float SB[32][CS + 4];  // B (transposed) in stage A, then decayed C in inter stage
  __shared__ float SX[32][DH + 4];  // X tile / h tile

  const int blk = blockIdx.x;
  const int bh  = blk >> 5;
  const int c   = blk & 31;
  const int tid = threadIdx.x;
  const int ty = tid >> 4, tx = tid & 15;

  const float* Ac = A + bh * SEQ + c * CS;
  const float* Xc = X + (size_t)(bh * SEQ + c * CS) * DH;
  const float* Bc = B + (size_t)(bh * SEQ + c * CS) * DS;
  const float* Cc = C + (size_t)(bh * SEQ + c * CS) * DS;
  const float* hst = hbuf + (size_t)blk * DS * DH;
  float* Yc = Y + (size_t)(bh * SEQ + c * CS) * DH;

  // cumsum
  if (tid < CS) csum[tid] = Ac[tid];
  __syncthreads();
  for (int off = 1; off < CS; off <<= 1) {
    float v = 0.f;
    if (tid < CS) { v = csum[tid]; if (tid >= off) v += csum[tid - off]; }
    __syncthreads();
    if (tid < CS) csum[tid] = v;
    __syncthreads();
  }

  float Yacc[8][4];
#pragma unroll
  for (int i = 0; i < 8; i++)
#pragma unroll
    for (int j = 0; j < 4; j++) Yacc[i][j] = 0.f;

  float Tacc[4][8][2];  // full 128x128 CB distributed: [jtile][ii][b]
#pragma unroll
  for (int t = 0; t < 4; t++)
#pragma unroll
    for (int i = 0; i < 8; i++)
#pragma unroll
      for (int b = 0; b < 2; b++) Tacc[t][i][b] = 0.f;

  // ---- stage A: CB = C * B^T, K = s (tiled by 32) ----
  for (int st = 0; st < 4; ++st) {
    const int s0 = st * 32;
#pragma unroll
    for (int m = 0; m < 4; m++) {
      int q = m * 256 + tid;          // float4 id 0..1023
      int i = q >> 3, s4 = q & 7;
      float4 v = *(const float4*)(Cc + (size_t)i * DS + s0 + s4 * 4);
      SA[s4 * 4 + 0][i] = v.x; SA[s4 * 4 + 1][i] = v.y;
      SA[s4 * 4 + 2][i] = v.z; SA[s4 * 4 + 3][i] = v.w;
      float4 w = *(const float4*)(Bc + (size_t)i * DS + s0 + s4 * 4);
      SB[s4 * 4 + 0][i] = w.x; SB[s4 * 4 + 1][i] = w.y;
      SB[s4 * 4 + 2][i] = w.z; SB[s4 * 4 + 3][i] = w.w;
    }
    __syncthreads();
#pragma unroll
    for (int k = 0; k < 32; k++) {
      float4 c0 = *(const float4*)(&SA[k][ty * 8]);
      float4 c1 = *(const float4*)(&SA[k][ty * 8 + 4]);
      float cc8[8] = {c0.x, c0.y, c0.z, c0.w, c1.x, c1.y, c1.z, c1.w};
#pragma unroll
      for (int t = 0; t < 4; t++) {
        float2 bv = *(const float2*)(&SB[k][t * 32 + tx * 2]);
#pragma unroll
        for (int i = 0; i < 8; i++) {
          Tacc[t][i][0] = fmaf(cc8[i], bv.x, Tacc[t][i][0]);
          Tacc[t][i][1] = fmaf(cc8[i], bv.y, Tacc[t][i][1]);
        }
      }
    }
    __syncthreads();
  }

  // ---- stage B: per j-tile, mask/decay -> LDS, Y += T * X ----
  for (int jt = 0; jt < 4; ++jt) {
    const int j0 = jt * 32;
#pragma unroll
    for (int i = 0; i < 8; i++) {
      int ri = ty * 8 + i;
#pragma unroll
      for (int b = 0; b < 2; b++) {
        int j = j0 + tx * 2 + b;
        float v = 0.f;
        if (ri >= j) v = Tacc[jt][i][b] * __expf(csum[ri] - csum[j]);
        SA[tx * 2 + b][ri] = v;
      }
    }
#pragma unroll
    for (int m = 0; m < 2; m++) {
      int q = m * 256 + tid;
      int r = q >> 4, c4 = q & 15;
      float4 v = *(const float4*)(Xc + (size_t)(j0 + r) * DH + c4 * 4);
      *(float4*)(&SX[r][c4 * 4]) = v;
    }
    __syncthreads();
#pragma unroll
    for (int k = 0; k < 32; k++) {
      float4 t0v = *(const float4*)(&SA[k][ty * 8]);
      float4 t1v = *(const float4*)(&SA[k][ty * 8 + 4]);
      float4 xv  = *(const float4*)(&SX[k][tx * 4]);
      float tt[8] = {t0v.x, t0v.y, t0v.z, t0v.w, t1v.x, t1v.y, t1v.z, t1v.w};
      float xx[4] = {xv.x, xv.y, xv.z, xv.w};
#pragma unroll
      for (int i = 0; i < 8; i++)
#pragma unroll
        for (int j = 0; j < 4; j++)
          Yacc[i][j] = fmaf(tt[i], xx[j], Yacc[i][j]);
    }
    __syncthreads();
  }

  // ---- inter: Y += diag(exp(csum)) * C * h_state ----
  for (int st = 0; st < 4; ++st) {
    const int s0 = st * 32;
#pragma unroll
    for (int m = 0; m < 4; m++) {
      int q = m * 256 + tid;
      int i = q >> 3, s4 = q & 7;
      float e = __expf(csum[i]);
      float4 v = *(const float4*)(Cc + (size_t)i * DS + s0 + s4 * 4);
      SB[s4 * 4 + 0][i] = v.x * e; SB[s4 * 4 + 1][i] = v.y * e;
      SB[s4 * 4 + 2][i] = v.z * e; SB[s4 * 4 + 3][i] = v.w * e;
    }
#pragma unroll
    for (int m = 0; m < 2; m++) {
      int q = m * 256 + tid;
      int r = q >> 4, c4 = q & 15;
      float4 v = *(const float4*)(hst + (size_t)(s0 + r) * DH + c4 * 4);
      *(float4*)(&SX[r][c4 * 4]) = v;
    }
    __syncthreads();
#pragma unroll
    for (int k = 0; k < 32; k++) {
      float4 c0 = *(const float4*)(&SB[k][ty * 8]);
      float4 c1 = *(const float4*)(&SB[k][ty * 8 + 4]);
      float4 hv = *(const float4*)(&SX[k][tx * 4]);
      float cc8[8] = {c0.x, c0.y, c0.z, c0.w, c1.x, c1.y, c1.z, c1.w};
      float hh[4] = {hv.x, hv.y, hv.z, hv.w};
#pragma unroll
      for (int i = 0; i < 8; i++)
#pragma unroll
        for (int j = 0; j < 4; j++)
          Yacc[i][j] = fmaf(cc8[i], hh[j], Yacc[i][j]);
    }
    __syncthreads();
  }

#pragma unroll
  for (int i = 0; i < 8; i++) {
    float4 v = {Yacc[i][0], Yacc[i][1], Yacc[i][2], Yacc[i][3]};
    *(float4*)(Yc + (size_t)(ty * 8 + i) * DH + tx * 4) = v;
  }
}

extern "C" void kernel_launch(void* const* d_in, const int* in_sizes, int n_in,
                              void* d_out, int out_size, void* d_ws, size_t ws_size,
                              hipStream_t stream)
{
  const float* X  = (const float*)d_in[0];
  const float* A  = (const float*)d_in[1];
  const float* B  = (const float*)d_in[2];
  const float* C  = (const float*)d_in[3];
  const float* h0 = (const float*)d_in[4];

  float* Y      = (float*)d_out;
  float* hfinal = Y + (size_t)NBH * SEQ * DH;          // 16777216 floats in

  float* hbuf = (float*)d_ws;                          // 64*32*8192 floats
  float* dtot = hbuf + (size_t)NBH * NC * DS * DH;     // 2048 floats

  dim3 blk(256);
  p1_hcontrib<<<dim3(NBH * NC), blk, 0, stream>>>(A, X, B, hbuf, dtot);
  p2_scan<<<dim3((NBH * DS * DH) / 256), blk, 0, stream>>>(h0, dtot, hbuf, hfinal);
  p3_y<<<dim3(NBH * NC), blk, 0, stream>>>(A, X, B, C, hbuf, Y);
}